// Round 9
// baseline (209.270 us; speedup 1.0000x reference)
//
#include <hip/hip_runtime.h>
#include <hip/hip_bf16.h>

typedef float f32x4 __attribute__((ext_vector_type(4)));
typedef __bf16 bf16x8 __attribute__((ext_vector_type(8)));

// ---------------------------------------------------------------------------
// GEMM1: h1(256x128) = x(256x256) @ w1(128x256)^T + b1
// ---------------------------------------------------------------------------
__global__ __launch_bounds__(128) void gemm1_k(const float* __restrict__ x,
                                               const float* __restrict__ w1,
                                               const float* __restrict__ b1,
                                               float* __restrict__ h1) {
    __shared__ float xs[256];
    const int m = blockIdx.x, t = threadIdx.x;
    xs[t] = x[m * 256 + t];
    xs[t + 128] = x[m * 256 + 128 + t];
    __syncthreads();
    float acc = b1[t];
    const float4* wr = (const float4*)(w1 + t * 256);
#pragma unroll 8
    for (int k4 = 0; k4 < 64; ++k4) {
        float4 w = wr[k4];
        acc += xs[k4 * 4 + 0] * w.x + xs[k4 * 4 + 1] * w.y +
               xs[k4 * 4 + 2] * w.z + xs[k4 * 4 + 3] * w.w;
    }
    h1[m * 128 + t] = acc;
}

// ---------------------------------------------------------------------------
// GEMM2: h2b = bf16 fragment-layout image of h1 @ w2^T + b2. XOR-FREE:
// byte(m, n) = (n>>6)*32768 + m*128 + ((n&63)>>3)*16 + (n&7)*2
// A wave's fragment read (16 rows x 64B) then pulls one 64B sector per row.
// ---------------------------------------------------------------------------
__global__ __launch_bounds__(256) void gemm2_k(const float* __restrict__ h1,
                                               const float* __restrict__ w2,
                                               const float* __restrict__ b2,
                                               char* __restrict__ h2b) {
    __shared__ float As[64][129];
    __shared__ float Bs[64][129];
    const int nb = blockIdx.x, mb = blockIdx.y, t = threadIdx.x;
#pragma unroll
    for (int i = 0; i < 8; ++i) {
        int idx = i * 256 + t;
        int row = idx >> 5, c4 = (idx & 31) * 4;
        float4 a = *(const float4*)(h1 + (mb * 64 + row) * 128 + c4);
        As[row][c4 + 0] = a.x; As[row][c4 + 1] = a.y;
        As[row][c4 + 2] = a.z; As[row][c4 + 3] = a.w;
        float4 bv = *(const float4*)(w2 + (nb * 64 + row) * 128 + c4);
        Bs[row][c4 + 0] = bv.x; Bs[row][c4 + 1] = bv.y;
        Bs[row][c4 + 2] = bv.z; Bs[row][c4 + 3] = bv.w;
    }
    __syncthreads();
    const int tx = t & 15, ty = t >> 4;
    float acc[4][4] = {};
#pragma unroll 4
    for (int k = 0; k < 128; ++k) {
        float a[4], b[4];
#pragma unroll
        for (int i = 0; i < 4; ++i) a[i] = As[ty * 4 + i][k];
#pragma unroll
        for (int j = 0; j < 4; ++j) b[j] = Bs[tx * 4 + j][k];
#pragma unroll
        for (int i = 0; i < 4; ++i)
#pragma unroll
            for (int j = 0; j < 4; ++j) acc[i][j] += a[i] * b[j];
    }
#pragma unroll
    for (int i = 0; i < 4; ++i)
#pragma unroll
        for (int j = 0; j < 4; ++j) {
            int m = mb * 64 + ty * 4 + i;
            int n = nb * 64 + tx * 4 + j;
            float v = acc[i][j] + b2[n];
            int kb = n >> 6, r = n & 63;
            int byte = kb * 32768 + m * 128 + (r >> 3) * 16 + (r & 7) * 2;
            *(__bf16*)(h2b + byte) = (__bf16)v;
        }
}

// ---------------------------------------------------------------------------
// GEMM3 v8: A fragments DIRECT from the L2-resident bf16 image (no LDS, no
// DMA, no xor). Only W staged: fp32 HBM -> regs -> bf16 -> LDS dbuf 2x8KB
// (XOR-swizzled for conflict-free ds_read). KS=2, grid 512, 512 thr (8 waves
// 4Mx2N). LDS=16KB, VGPR<=128 (launch_bounds 512,4) -> 2 blocks/CU TLP.
// No inline asm: barriers guard only the 8KB W buffer; draining is cheap.
// ---------------------------------------------------------------------------
__global__ __launch_bounds__(512, 4) void gemm3_k(const char* __restrict__ Ab,
                                                  const float* __restrict__ W,
                                                  char* __restrict__ parts) {
    __shared__ __align__(16) char lds[16384];  // W dbuf 2x8KB
    const int tid = threadIdx.x;
    const int nb = blockIdx.x >> 1, ks = blockIdx.x & 1;
    const int n0 = nb * 64;
    const int lane = tid & 63, wid = tid >> 6;
    const int mrow = tid >> 3, kb8 = tid & 7;
    const int kt0 = ks * 32;
    const int lr = lane & 15, lq = lane >> 4;
    const int wm = wid >> 1, wn = wid & 1;

    const float* Wlane = W + (size_t)(n0 + mrow) * 4096 + kb8 * 8;
    // A fragment base: row = wm*64 + mi*16 + lr; byte = row*128 + (kk*4+lq)*16
    const char* Abase = Ab + (wm * 64 + lr) * 128 + lq * 16;

    auto loadW = [&](int kt, float4& d0, float4& d1) {
        const float* q = Wlane + (size_t)kt * 64;
        d0 = *(const float4*)q;
        d1 = *(const float4*)(q + 4);
    };
    auto storeW2 = [&](const float4& a, const float4& b, int buf) {
        bf16x8 p;
        p[0] = (__bf16)a.x; p[1] = (__bf16)a.y; p[2] = (__bf16)a.z; p[3] = (__bf16)a.w;
        p[4] = (__bf16)b.x; p[5] = (__bf16)b.y; p[6] = (__bf16)b.z; p[7] = (__bf16)b.w;
        *(bf16x8*)(lds + buf * 8192 +
                   ((mrow * 128 + kb8 * 16) ^ ((mrow & 7) << 4))) = p;
    };

    f32x4 acc[4][2];
    const f32x4 zero = {0.f, 0.f, 0.f, 0.f};
#pragma unroll
    for (int mi = 0; mi < 4; ++mi)
#pragma unroll
        for (int ni = 0; ni < 2; ++ni) acc[mi][ni] = zero;

    auto mfma_tile = [&](int kt, const char* Wc) {
        const char* Ak = Abase + (size_t)kt * 32768;
#pragma unroll
        for (int kk = 0; kk < 2; ++kk) {
            bf16x8 af[4], bfv[2];
#pragma unroll
            for (int mi = 0; mi < 4; ++mi)
                af[mi] = *(const bf16x8*)(Ak + mi * 2048 + kk * 64);
#pragma unroll
            for (int ni = 0; ni < 2; ++ni) {
                int n = wn * 32 + ni * 16 + lr;
                bfv[ni] = *(const bf16x8*)(Wc + ((n * 128 + (kk * 4 + lq) * 16) ^ ((n & 7) << 4)));
            }
#pragma unroll
            for (int mi = 0; mi < 4; ++mi)
#pragma unroll
                for (int ni = 0; ni < 2; ++ni)
                    acc[mi][ni] = __builtin_amdgcn_mfma_f32_16x16x32_bf16(
                        af[mi], bfv[ni], acc[mi][ni], 0, 0, 0);
        }
    };

    // prologue
    float4 wc0, wc1;
    loadW(kt0, wc0, wc1);
    storeW2(wc0, wc1, 0);
    __syncthreads();

#pragma unroll 1
    for (int t = 0; t < 32; ++t) {
        const int cur = t & 1;
        float4 wn0, wn1;
        if (t < 31) loadW(kt0 + t + 1, wn0, wn1);   // issue early, lands during MFMA
        mfma_tile(kt0 + t, lds + cur * 8192);
        __syncthreads();                             // all reads of buf cur done
        if (t < 31) storeW2(wn0, wn1, cur ^ 1);
        __syncthreads();                             // buf cur^1 visible
    }

    __bf16* P = (__bf16*)(parts + ks * 8388608);
#pragma unroll
    for (int mi = 0; mi < 4; ++mi)
#pragma unroll
        for (int ni = 0; ni < 2; ++ni) {
            const int n = n0 + wn * 32 + ni * 16 + lr;
#pragma unroll
            for (int r = 0; r < 4; ++r) {
                int m = wm * 64 + mi * 16 + lq * 4 + r;
                P[m * 16384 + n] = (__bf16)acc[mi][ni][r];
            }
        }
}

// ---------------------------------------------------------------------------
// Fused conv x5 (bf16 MFMA) + square + Sinkhorn. One block per batch element.
// Staging sums the two gemm3 partials and adds b3.
// ---------------------------------------------------------------------------
template <int CIN, int COUT, int DIL, int MT, int NT>
__device__ __forceinline__ void conv_core(const char* xt, char* wl,
                                          const float* __restrict__ w,
                                          f32x4 (&acc)[MT][NT], int tid) {
    constexpr int RB = CIN * 2;
    const int lane = tid & 63, wid = tid >> 6;
    const int lr = lane & 15, lq = lane >> 4;
    const int cobase = wid * (COUT / 4);
    const f32x4 zero = {0.f, 0.f, 0.f, 0.f};
#pragma unroll
    for (int mi = 0; mi < MT; ++mi)
#pragma unroll
        for (int ni = 0; ni < NT; ++ni) acc[mi][ni] = zero;

    for (int cic = 0; cic < CIN / 32; ++cic) {
        for (int idx = tid; idx < COUT * 4; idx += 256) {
            int co = idx >> 2, cib = idx & 3, ci0 = cic * 32 + cib * 8;
            const float* src = w + co * (CIN * 3) + ci0 * 3;
            float v[24];
#pragma unroll
            for (int u = 0; u < 6; ++u) {
                float4 f = *(const float4*)(src + u * 4);
                v[u * 4 + 0] = f.x; v[u * 4 + 1] = f.y;
                v[u * 4 + 2] = f.z; v[u * 4 + 3] = f.w;
            }
#pragma unroll
            for (int tp = 0; tp < 3; ++tp) {
                bf16x8 pk;
#pragma unroll
                for (int j = 0; j < 8; ++j) pk[j] = (__bf16)v[j * 3 + tp];
                *(bf16x8*)(wl + ((tp * 4 + cib) * COUT + co) * 16) = pk;
            }
        }
        __syncthreads();
#pragma unroll
        for (int tp = 0; tp < 3; ++tp) {
            bf16x8 af[MT];
#pragma unroll
            for (int mi = 0; mi < MT; ++mi)
                af[mi] = *(const bf16x8*)(wl + ((tp * 4 + lq) * COUT + cobase + mi * 16 + lr) * 16);
            bf16x8 bfr[NT];
#pragma unroll
            for (int ni = 0; ni < NT; ++ni) {
                int colX = ni * 16 + lr + tp * DIL;
                bfr[ni] = *(const bf16x8*)(xt + ((colX * RB + (cic * 4 + lq) * 16) ^ ((colX & 7) << 4)));
            }
#pragma unroll
            for (int mi = 0; mi < MT; ++mi)
#pragma unroll
                for (int ni = 0; ni < NT; ++ni)
                    acc[mi][ni] = __builtin_amdgcn_mfma_f32_16x16x32_bf16(
                        af[mi], bfr[ni], acc[mi][ni], 0, 0, 0);
        }
        __syncthreads();
    }
}

template <int COUT, int LOUT, int MT, int NT>
__device__ __forceinline__ void write_xt(char* xt_out, const f32x4 (&acc)[MT][NT],
                                         const float* __restrict__ bias, int tid) {
    constexpr int RBO = COUT * 2;
    const int lane = tid & 63, wid = tid >> 6;
    const int lr = lane & 15, lq = lane >> 4;
    const int cobase = wid * (COUT / 4);
#pragma unroll
    for (int mi = 0; mi < MT; ++mi)
#pragma unroll
        for (int ni = 0; ni < NT; ++ni) {
            int l = ni * 16 + lr;
            if (l < LOUT) {
#pragma unroll
                for (int r = 0; r < 4; ++r) {
                    int co = cobase + mi * 16 + lq * 4 + r;
                    float y = acc[mi][ni][r] + bias[co];
                    int byte = (l * RBO + ((co >> 3) << 4) + (co & 7) * 2) ^ ((l & 7) << 4);
                    *(__bf16*)(xt_out + byte) = (__bf16)y;
                }
            }
        }
}

__global__ __launch_bounds__(256, 1) void convsink_k(
    const char* __restrict__ parts, const float* __restrict__ b3,
    const float* __restrict__ cw1, const float* __restrict__ cb1,
    const float* __restrict__ cw2, const float* __restrict__ cb2,
    const float* __restrict__ cw3, const float* __restrict__ cb3,
    const float* __restrict__ cw4, const float* __restrict__ cb4,
    const float* __restrict__ cw5, const float* __restrict__ cb5,
    float* __restrict__ out) {
    __shared__ __align__(16) char lds[34816 + 31488 + 36864 + 16640];
    char* xtA = lds;
    char* xtB = lds + 34816;
    char* wl = lds + 34816 + 31488;
    float* S = (float*)(lds + 34816 + 31488 + 36864);

    const int b = blockIdx.x, tid = threadIdx.x;
    const __bf16* p0 = (const __bf16*)parts + (size_t)b * 16384;
    const __bf16* p1 = (const __bf16*)(parts + 8388608) + (size_t)b * 16384;

#pragma unroll
    for (int i = 0; i < 8; ++i) {
        int idx = i * 256 + tid;
        int l = idx & 127, cib = idx >> 7;
        bf16x8 p;
#pragma unroll
        for (int j = 0; j < 8; ++j) {
            int n = (cib * 8 + j) * 128 + l;
            float v = (float)p0[n] + (float)p1[n] + b3[n];
            p[j] = (__bf16)v;
        }
        *(bf16x8*)(xtA + ((l * 256 + cib * 16) ^ ((l & 7) << 4))) = p;
    }
    __syncthreads();

    {
        f32x4 acc[3][5];
        conv_core<128, 192, 28, 3, 5>(xtA, wl, cw1, acc, tid);
        write_xt<192, 72, 3, 5>(xtB, acc, cb1, tid);
    }
    __syncthreads();
    {
        f32x4 acc[2][5];
        conv_core<192, 128, 1, 2, 5>(xtB, wl, cw2, acc, tid);
        write_xt<128, 70, 2, 5>(xtA, acc, cb2, tid);
    }
    __syncthreads();
    {
        f32x4 acc[1][5];
        conv_core<128, 64, 1, 1, 5>(xtA, wl, cw3, acc, tid);
        write_xt<64, 68, 1, 5>(xtB, acc, cb3, tid);
    }
    __syncthreads();
    {
        f32x4 acc[1][5];
        conv_core<64, 64, 1, 1, 5>(xtB, wl, cw4, acc, tid);
        write_xt<64, 66, 1, 5>(xtA, acc, cb4, tid);
    }
    __syncthreads();
    {
        f32x4 acc[1][4];
        conv_core<64, 64, 1, 1, 4>(xtA, wl, cw5, acc, tid);
        const int lane = tid & 63, wid = tid >> 6;
        const int lr = lane & 15, lq = lane >> 4;
        const int cobase = wid * 16;
#pragma unroll
        for (int ni = 0; ni < 4; ++ni) {
            int l = ni * 16 + lr;
#pragma unroll
            for (int r = 0; r < 4; ++r) {
                int co = cobase + lq * 4 + r;
                float y = acc[0][ni][r] + cb5[co];
                S[co * 65 + l] = y * y + 0.001f;
            }
        }
    }
    __syncthreads();

    const int q = tid & 3, rid = tid >> 2;
    for (int it = 0; it < 10; ++it) {
        float p = 0.f;
#pragma unroll
        for (int j = 0; j < 16; ++j) p += S[rid * 65 + q * 16 + j];
        p += __shfl_xor(p, 1);
        p += __shfl_xor(p, 2);
        float inv = 1.0f / p;
#pragma unroll
        for (int j = 0; j < 16; ++j) S[rid * 65 + q * 16 + j] *= inv;
        __syncthreads();
        float c = 0.f;
#pragma unroll
        for (int i = 0; i < 16; ++i) c += S[(q * 16 + i) * 65 + rid];
        c += __shfl_xor(c, 1);
        c += __shfl_xor(c, 2);
        float invc = 1.0f / c;
#pragma unroll
        for (int i = 0; i < 16; ++i) S[(q * 16 + i) * 65 + rid] *= invc;
        __syncthreads();
    }

#pragma unroll
    for (int i = 0; i < 16; ++i) {
        int idx = i * 256 + tid;
        out[b * 4096 + idx] = S[(idx >> 6) * 65 + (idx & 63)];
    }
}

// ---------------------------------------------------------------------------
extern "C" void kernel_launch(void* const* d_in, const int* in_sizes, int n_in,
                              void* d_out, int out_size, void* d_ws, size_t ws_size,
                              hipStream_t stream) {
    const float* x = (const float*)d_in[0];
    const float* w1 = (const float*)d_in[1];
    const float* b1 = (const float*)d_in[2];
    const float* w2 = (const float*)d_in[3];
    const float* b2 = (const float*)d_in[4];
    const float* w3 = (const float*)d_in[5];
    const float* b3 = (const float*)d_in[6];
    const float* cw1 = (const float*)d_in[7];
    const float* cb1 = (const float*)d_in[8];
    const float* cw2 = (const float*)d_in[9];
    const float* cb2 = (const float*)d_in[10];
    const float* cw3 = (const float*)d_in[11];
    const float* cb3 = (const float*)d_in[12];
    const float* cw4 = (const float*)d_in[13];
    const float* cb4 = (const float*)d_in[14];
    const float* cw5 = (const float*)d_in[15];
    const float* cb5 = (const float*)d_in[16];
    float* out = (float*)d_out;

    char* ws = (char*)d_ws;
    float* h1 = (float*)(ws);             // 131072 B
    char* h2b = ws + 131072;              // 2 MB bf16 fragment image (xor-free)
    char* parts = ws + 131072 + 2097152;  // 2 x 8 MB bf16 partials

    gemm1_k<<<256, 128, 0, stream>>>(x, w1, b1, h1);
    gemm2_k<<<dim3(64, 4), 256, 0, stream>>>(h1, w2, b2, h2b);
    gemm3_k<<<512, 512, 0, stream>>>(h2b, w3, parts);
    convsink_k<<<256, 256, 0, stream>>>(parts, b3, cw1, cb1, cw2, cb2,
                                        cw3, cb3, cw4, cb4, cw5, cb5, out);
}

// Round 10
// 156.768 us; speedup vs baseline: 1.3349x; 1.3349x over previous
//
#include <hip/hip_runtime.h>
#include <hip/hip_bf16.h>

typedef float f32x4 __attribute__((ext_vector_type(4)));
typedef __bf16 bf16x8 __attribute__((ext_vector_type(8)));

typedef __attribute__((address_space(1))) const unsigned int as1_uint;
typedef __attribute__((address_space(3))) unsigned int as3_uint;

// ---------------------------------------------------------------------------
// GEMM1: h1(256x128) = x(256x256) @ w1(128x256)^T + b1
// ---------------------------------------------------------------------------
__global__ __launch_bounds__(128) void gemm1_k(const float* __restrict__ x,
                                               const float* __restrict__ w1,
                                               const float* __restrict__ b1,
                                               float* __restrict__ h1) {
    __shared__ float xs[256];
    const int m = blockIdx.x, t = threadIdx.x;
    xs[t] = x[m * 256 + t];
    xs[t + 128] = x[m * 256 + 128 + t];
    __syncthreads();
    float acc = b1[t];
    const float4* wr = (const float4*)(w1 + t * 256);
#pragma unroll 8
    for (int k4 = 0; k4 < 64; ++k4) {
        float4 w = wr[k4];
        acc += xs[k4 * 4 + 0] * w.x + xs[k4 * 4 + 1] * w.y +
               xs[k4 * 4 + 2] * w.z + xs[k4 * 4 + 3] * w.w;
    }
    h1[m * 128 + t] = acc;
}

// ---------------------------------------------------------------------------
// GEMM2: h2b = bf16 pre-swizzled "LDS image" of h1 @ w2^T + b2.
// byte(m, n) = (n>>6)*32768 + ((m*128 + ((n&63)>>3)*16) ^ ((m&7)<<4)) + (n&7)*2
// ---------------------------------------------------------------------------
__global__ __launch_bounds__(256) void gemm2_k(const float* __restrict__ h1,
                                               const float* __restrict__ w2,
                                               const float* __restrict__ b2,
                                               char* __restrict__ h2b) {
    __shared__ float As[64][129];
    __shared__ float Bs[64][129];
    const int nb = blockIdx.x, mb = blockIdx.y, t = threadIdx.x;
#pragma unroll
    for (int i = 0; i < 8; ++i) {
        int idx = i * 256 + t;
        int row = idx >> 5, c4 = (idx & 31) * 4;
        float4 a = *(const float4*)(h1 + (mb * 64 + row) * 128 + c4);
        As[row][c4 + 0] = a.x; As[row][c4 + 1] = a.y;
        As[row][c4 + 2] = a.z; As[row][c4 + 3] = a.w;
        float4 bv = *(const float4*)(w2 + (nb * 64 + row) * 128 + c4);
        Bs[row][c4 + 0] = bv.x; Bs[row][c4 + 1] = bv.y;
        Bs[row][c4 + 2] = bv.z; Bs[row][c4 + 3] = bv.w;
    }
    __syncthreads();
    const int tx = t & 15, ty = t >> 4;
    float acc[4][4] = {};
#pragma unroll 4
    for (int k = 0; k < 128; ++k) {
        float a[4], b[4];
#pragma unroll
        for (int i = 0; i < 4; ++i) a[i] = As[ty * 4 + i][k];
#pragma unroll
        for (int j = 0; j < 4; ++j) b[j] = Bs[tx * 4 + j][k];
#pragma unroll
        for (int i = 0; i < 4; ++i)
#pragma unroll
            for (int j = 0; j < 4; ++j) acc[i][j] += a[i] * b[j];
    }
#pragma unroll
    for (int i = 0; i < 4; ++i)
#pragma unroll
        for (int j = 0; j < 4; ++j) {
            int m = mb * 64 + ty * 4 + i;
            int n = nb * 64 + tx * 4 + j;
            float v = acc[i][j] + b2[n];
            int kb = n >> 6, r = n & 63;
            int byte = kb * 32768 + ((m * 128 + (r >> 3) * 16) ^ ((m & 7) << 4)) + (r & 7) * 2;
            *(__bf16*)(h2b + byte) = (__bf16)v;
        }
}

// ---------------------------------------------------------------------------
// GEMM3 v9: FULLY DMA-staged ring-3 pipeline, counted vmcnt, ONE barrier/step.
// No register staging anywhere -> nothing for the compiler to sink.
//   A: bf16 pre-swizzled image, linear DMA into ring slot (3x32KB).
//   W: fp32, DMA with SOURCE-address granule-XOR sw(n)=((n&7)<<1)|((n>>3)&1)
//      (LDS dest linear per m173); fragment reads are 16-distinct-granule ->
//      conflict-free; cvt fp32->bf16 at fragment-read time (no staging regs).
// Per step t: issue 6 DMAs for (t+2) ; MFMA(t) ; vmcnt(6) [retire (t+1),
// keep (t+2) in flight] ; raw s_barrier. grid 256, 512 thr, 147KB LDS.
// ---------------------------------------------------------------------------
__global__ __launch_bounds__(512, 1) void gemm3_k(const char* __restrict__ Ab,
                                                  const float* __restrict__ W,
                                                  const float* __restrict__ bias,
                                                  float* __restrict__ C) {
    __shared__ __align__(16) char lds[147456];  // A ring 3x32768 @0; W ring 3x16384 @98304
    const int tid = threadIdx.x;
    const int n0 = blockIdx.x * 64;
    const int lane = tid & 63, wid = tid >> 6;
    const int lr = lane & 15, lq = lane >> 4;
    const int wm = wid >> 1, wn = wid & 1;

    // A DMA: linear copy (image already fragment-swizzled by gemm2)
    const char* Asrc = Ab + wid * 4096 + lane * 16;  // + t*32768, +i*1024

    // W DMA: 2 granules (16B) per thread, source pre-swizzled
    const int n_a = wid * 4 + (lane >> 4);  // rows 0..31 of tile
    const int n_b = 32 + n_a;               // rows 32..63
    const int g_d = lane & 15;              // dest in-row granule
    const int sw_a = ((n_a & 7) << 1) | ((n_a >> 3) & 1);
    const int sw_b = ((n_b & 7) << 1) | ((n_b >> 3) & 1);
    const char* WsrcA = (const char*)W + (size_t)(n0 + n_a) * 16384 + (g_d ^ sw_a) * 16;
    const char* WsrcB = (const char*)W + (size_t)(n0 + n_b) * 16384 + (g_d ^ sw_b) * 16;

#define ISSUE(kt, s)                                                                  \
    {                                                                                 \
        const char* _a = Asrc + (size_t)(kt) * 32768;                                 \
        char* _ad = lds + (s) * 32768 + wid * 4096;                                   \
        __builtin_amdgcn_global_load_lds((as1_uint*)(_a), (as3_uint*)(_ad), 16, 0, 0);              \
        __builtin_amdgcn_global_load_lds((as1_uint*)(_a + 1024), (as3_uint*)(_ad + 1024), 16, 0, 0);  \
        __builtin_amdgcn_global_load_lds((as1_uint*)(_a + 2048), (as3_uint*)(_ad + 2048), 16, 0, 0);  \
        __builtin_amdgcn_global_load_lds((as1_uint*)(_a + 3072), (as3_uint*)(_ad + 3072), 16, 0, 0);  \
        const char* _wa = WsrcA + (size_t)(kt) * 256;                                 \
        const char* _wb = WsrcB + (size_t)(kt) * 256;                                 \
        char* _wd = lds + 98304 + (s) * 16384 + wid * 1024;                           \
        __builtin_amdgcn_global_load_lds((as1_uint*)(_wa), (as3_uint*)(_wd), 16, 0, 0);             \
        __builtin_amdgcn_global_load_lds((as1_uint*)(_wb), (as3_uint*)(_wd + 8192), 16, 0, 0);      \
    }

    f32x4 acc[4][2];
    const f32x4 zero = {0.f, 0.f, 0.f, 0.f};
#pragma unroll
    for (int mi = 0; mi < 4; ++mi)
#pragma unroll
        for (int ni = 0; ni < 2; ++ni) acc[mi][ni] = zero;

    // lane-constant pieces for W fragment reads
    const int nfr[2] = {wn * 32 + lr, wn * 32 + 16 + lr};
    int wfr[2][2];  // [ni][half]: swizzled granule offsets, per kk add base
#pragma unroll
    for (int ni = 0; ni < 2; ++ni) {
        int n = nfr[ni];
        int s_n = ((n & 7) << 1) | ((n >> 3) & 1);
        wfr[ni][0] = n * 256 + (s_n ^ 0) * 0;  // placeholder, computed per kk below
        wfr[ni][1] = s_n;
    }

    auto mfma_tile = [&](int s) {
        const char* Ac = lds + s * 32768;
        const char* Wc = lds + 98304 + s * 16384;
#pragma unroll
        for (int kk = 0; kk < 2; ++kk) {
            const int kb = kk * 4 + lq;
            bf16x8 af[4], bfv[2];
#pragma unroll
            for (int mi = 0; mi < 4; ++mi) {
                int m = wm * 64 + mi * 16 + lr;
                af[mi] = *(const bf16x8*)(Ac + ((m * 128 + kb * 16) ^ ((m & 7) << 4)));
            }
#pragma unroll
            for (int ni = 0; ni < 2; ++ni) {
                int n = nfr[ni];
                int s_n = wfr[ni][1];
                int g0 = kb * 2;
                float4 f0 = *(const float4*)(Wc + n * 256 + ((g0 ^ s_n) * 16));
                float4 f1 = *(const float4*)(Wc + n * 256 + (((g0 + 1) ^ s_n) * 16));
                bf16x8 p;
                p[0] = (__bf16)f0.x; p[1] = (__bf16)f0.y; p[2] = (__bf16)f0.z; p[3] = (__bf16)f0.w;
                p[4] = (__bf16)f1.x; p[5] = (__bf16)f1.y; p[6] = (__bf16)f1.z; p[7] = (__bf16)f1.w;
                bfv[ni] = p;
            }
#pragma unroll
            for (int mi = 0; mi < 4; ++mi)
#pragma unroll
                for (int ni = 0; ni < 2; ++ni)
                    acc[mi][ni] = __builtin_amdgcn_mfma_f32_16x16x32_bf16(
                        af[mi], bfv[ni], acc[mi][ni], 0, 0, 0);
        }
    };

    // prologue: tiles 0,1 in flight; wait tile 0 (retire 6, leave 6)
    ISSUE(0, 0);
    ISSUE(1, 1);
    asm volatile("s_waitcnt vmcnt(6)" ::: "memory");
    __builtin_amdgcn_sched_barrier(0);
    __builtin_amdgcn_s_barrier();

    int s = 0;
#pragma unroll 1
    for (int t = 0; t < 64; ++t) {
        int s2 = s + 2;
        if (s2 >= 3) s2 -= 3;
        if (t < 62) ISSUE(t + 2, s2);
        mfma_tile(s);
        if (t < 62) {
            asm volatile("s_waitcnt vmcnt(6)" ::: "memory");
        } else if (t == 62) {
            asm volatile("s_waitcnt vmcnt(0)" ::: "memory");
        }
        __builtin_amdgcn_sched_barrier(0);
        if (t < 63) __builtin_amdgcn_s_barrier();
        s = (s == 2) ? 0 : s + 1;
    }
#undef ISSUE

    float bv[2];
#pragma unroll
    for (int ni = 0; ni < 2; ++ni) bv[ni] = bias[n0 + wn * 32 + ni * 16 + lr];
#pragma unroll
    for (int mi = 0; mi < 4; ++mi)
#pragma unroll
        for (int ni = 0; ni < 2; ++ni) {
            const int n = n0 + wn * 32 + ni * 16 + lr;
#pragma unroll
            for (int r = 0; r < 4; ++r) {
                int m = wm * 64 + mi * 16 + lq * 4 + r;
                C[m * 16384 + n] = acc[mi][ni][r] + bv[ni];
            }
        }
}

// ---------------------------------------------------------------------------
// Fused conv x5 (bf16 MFMA) + square + Sinkhorn. One block per batch element.
// ---------------------------------------------------------------------------
template <int CIN, int COUT, int DIL, int MT, int NT>
__device__ __forceinline__ void conv_core(const char* xt, char* wl,
                                          const float* __restrict__ w,
                                          f32x4 (&acc)[MT][NT], int tid) {
    constexpr int RB = CIN * 2;
    const int lane = tid & 63, wid = tid >> 6;
    const int lr = lane & 15, lq = lane >> 4;
    const int cobase = wid * (COUT / 4);
    const f32x4 zero = {0.f, 0.f, 0.f, 0.f};
#pragma unroll
    for (int mi = 0; mi < MT; ++mi)
#pragma unroll
        for (int ni = 0; ni < NT; ++ni) acc[mi][ni] = zero;

    for (int cic = 0; cic < CIN / 32; ++cic) {
        for (int idx = tid; idx < COUT * 4; idx += 256) {
            int co = idx >> 2, cib = idx & 3, ci0 = cic * 32 + cib * 8;
            const float* src = w + co * (CIN * 3) + ci0 * 3;
            float v[24];
#pragma unroll
            for (int u = 0; u < 6; ++u) {
                float4 f = *(const float4*)(src + u * 4);
                v[u * 4 + 0] = f.x; v[u * 4 + 1] = f.y;
                v[u * 4 + 2] = f.z; v[u * 4 + 3] = f.w;
            }
#pragma unroll
            for (int tp = 0; tp < 3; ++tp) {
                bf16x8 pk;
#pragma unroll
                for (int j = 0; j < 8; ++j) pk[j] = (__bf16)v[j * 3 + tp];
                *(bf16x8*)(wl + ((tp * 4 + cib) * COUT + co) * 16) = pk;
            }
        }
        __syncthreads();
#pragma unroll
        for (int tp = 0; tp < 3; ++tp) {
            bf16x8 af[MT];
#pragma unroll
            for (int mi = 0; mi < MT; ++mi)
                af[mi] = *(const bf16x8*)(wl + ((tp * 4 + lq) * COUT + cobase + mi * 16 + lr) * 16);
            bf16x8 bfr[NT];
#pragma unroll
            for (int ni = 0; ni < NT; ++ni) {
                int colX = ni * 16 + lr + tp * DIL;
                bfr[ni] = *(const bf16x8*)(xt + ((colX * RB + (cic * 4 + lq) * 16) ^ ((colX & 7) << 4)));
            }
#pragma unroll
            for (int mi = 0; mi < MT; ++mi)
#pragma unroll
                for (int ni = 0; ni < NT; ++ni)
                    acc[mi][ni] = __builtin_amdgcn_mfma_f32_16x16x32_bf16(
                        af[mi], bfr[ni], acc[mi][ni], 0, 0, 0);
        }
        __syncthreads();
    }
}

template <int COUT, int LOUT, int MT, int NT>
__device__ __forceinline__ void write_xt(char* xt_out, const f32x4 (&acc)[MT][NT],
                                         const float* __restrict__ bias, int tid) {
    constexpr int RBO = COUT * 2;
    const int lane = tid & 63, wid = tid >> 6;
    const int lr = lane & 15, lq = lane >> 4;
    const int cobase = wid * (COUT / 4);
#pragma unroll
    for (int mi = 0; mi < MT; ++mi)
#pragma unroll
        for (int ni = 0; ni < NT; ++ni) {
            int l = ni * 16 + lr;
            if (l < LOUT) {
#pragma unroll
                for (int r = 0; r < 4; ++r) {
                    int co = cobase + mi * 16 + lq * 4 + r;
                    float y = acc[mi][ni][r] + bias[co];
                    int byte = (l * RBO + ((co >> 3) << 4) + (co & 7) * 2) ^ ((l & 7) << 4);
                    *(__bf16*)(xt_out + byte) = (__bf16)y;
                }
            }
        }
}

__global__ __launch_bounds__(256, 1) void convsink_k(
    const float* __restrict__ h3,
    const float* __restrict__ cw1, const float* __restrict__ cb1,
    const float* __restrict__ cw2, const float* __restrict__ cb2,
    const float* __restrict__ cw3, const float* __restrict__ cb3,
    const float* __restrict__ cw4, const float* __restrict__ cb4,
    const float* __restrict__ cw5, const float* __restrict__ cb5,
    float* __restrict__ out) {
    __shared__ __align__(16) char lds[34816 + 31488 + 36864 + 16640];
    char* xtA = lds;
    char* xtB = lds + 34816;
    char* wl = lds + 34816 + 31488;
    float* S = (float*)(lds + 34816 + 31488 + 36864);

    const int b = blockIdx.x, tid = threadIdx.x;
    const float* src = h3 + b * 16384;

#pragma unroll
    for (int i = 0; i < 8; ++i) {
        int idx = i * 256 + tid;
        int l = idx & 127, cib = idx >> 7;
        bf16x8 p;
#pragma unroll
        for (int j = 0; j < 8; ++j) p[j] = (__bf16)src[(cib * 8 + j) * 128 + l];
        *(bf16x8*)(xtA + ((l * 256 + cib * 16) ^ ((l & 7) << 4))) = p;
    }
    __syncthreads();

    {
        f32x4 acc[3][5];
        conv_core<128, 192, 28, 3, 5>(xtA, wl, cw1, acc, tid);
        write_xt<192, 72, 3, 5>(xtB, acc, cb1, tid);
    }
    __syncthreads();
    {
        f32x4 acc[2][5];
        conv_core<192, 128, 1, 2, 5>(xtB, wl, cw2, acc, tid);
        write_xt<128, 70, 2, 5>(xtA, acc, cb2, tid);
    }
    __syncthreads();
    {
        f32x4 acc[1][5];
        conv_core<128, 64, 1, 1, 5>(xtA, wl, cw3, acc, tid);
        write_xt<64, 68, 1, 5>(xtB, acc, cb3, tid);
    }
    __syncthreads();
    {
        f32x4 acc[1][5];
        conv_core<64, 64, 1, 1, 5>(xtB, wl, cw4, acc, tid);
        write_xt<64, 66, 1, 5>(xtA, acc, cb4, tid);
    }
    __syncthreads();
    {
        f32x4 acc[1][4];
        conv_core<64, 64, 1, 1, 4>(xtA, wl, cw5, acc, tid);
        const int lane = tid & 63, wid = tid >> 6;
        const int lr = lane & 15, lq = lane >> 4;
        const int cobase = wid * 16;
#pragma unroll
        for (int ni = 0; ni < 4; ++ni) {
            int l = ni * 16 + lr;
#pragma unroll
            for (int r = 0; r < 4; ++r) {
                int co = cobase + lq * 4 + r;
                float y = acc[0][ni][r] + cb5[co];
                S[co * 65 + l] = y * y + 0.001f;
            }
        }
    }
    __syncthreads();

    const int q = tid & 3, rid = tid >> 2;
    for (int it = 0; it < 10; ++it) {
        float p = 0.f;
#pragma unroll
        for (int j = 0; j < 16; ++j) p += S[rid * 65 + q * 16 + j];
        p += __shfl_xor(p, 1);
        p += __shfl_xor(p, 2);
        float inv = 1.0f / p;
#pragma unroll
        for (int j = 0; j < 16; ++j) S[rid * 65 + q * 16 + j] *= inv;
        __syncthreads();
        float c = 0.f;
#pragma unroll
        for (int i = 0; i < 16; ++i) c += S[(q * 16 + i) * 65 + rid];
        c += __shfl_xor(c, 1);
        c += __shfl_xor(c, 2);
        float invc = 1.0f / c;
#pragma unroll
        for (int i = 0; i < 16; ++i) S[(q * 16 + i) * 65 + rid] *= invc;
        __syncthreads();
    }

#pragma unroll
    for (int i = 0; i < 16; ++i) {
        int idx = i * 256 + tid;
        out[b * 4096 + idx] = S[(idx >> 6) * 65 + (idx & 63)];
    }
}

// ---------------------------------------------------------------------------
extern "C" void kernel_launch(void* const* d_in, const int* in_sizes, int n_in,
                              void* d_out, int out_size, void* d_ws, size_t ws_size,
                              hipStream_t stream) {
    const float* x = (const float*)d_in[0];
    const float* w1 = (const float*)d_in[1];
    const float* b1 = (const float*)d_in[2];
    const float* w2 = (const float*)d_in[3];
    const float* b2 = (const float*)d_in[4];
    const float* w3 = (const float*)d_in[5];
    const float* b3 = (const float*)d_in[6];
    const float* cw1 = (const float*)d_in[7];
    const float* cb1 = (const float*)d_in[8];
    const float* cw2 = (const float*)d_in[9];
    const float* cb2 = (const float*)d_in[10];
    const float* cw3 = (const float*)d_in[11];
    const float* cb3 = (const float*)d_in[12];
    const float* cw4 = (const float*)d_in[13];
    const float* cb4 = (const float*)d_in[14];
    const float* cw5 = (const float*)d_in[15];
    const float* cb5 = (const float*)d_in[16];
    float* out = (float*)d_out;

    char* ws = (char*)d_ws;
    float* h1 = (float*)(ws);                      // 131072 B
    char* h2b = ws + 131072;                       // 2 MB bf16 pre-swizzled image
    float* h3 = (float*)(ws + 131072 + 2097152);   // 16 MB

    gemm1_k<<<256, 128, 0, stream>>>(x, w1, b1, h1);
    gemm2_k<<<dim3(64, 4), 256, 0, stream>>>(h1, w2, b2, h2b);
    gemm3_k<<<256, 512, 0, stream>>>(h2b, w3, b3, h3);
    convsink_k<<<256, 256, 0, stream>>>(h3, cw1, cb1, cw2, cb2, cw3, cb3,
                                        cw4, cb4, cw5, cb5, out);
}

// Round 11
// 153.913 us; speedup vs baseline: 1.3597x; 1.0186x over previous
//
#include <hip/hip_runtime.h>
#include <hip/hip_bf16.h>

typedef float f32x4 __attribute__((ext_vector_type(4)));
typedef __bf16 bf16x8 __attribute__((ext_vector_type(8)));

typedef __attribute__((address_space(1))) const unsigned int as1_uint;
typedef __attribute__((address_space(3))) unsigned int as3_uint;

// ---------------------------------------------------------------------------
// GEMM1: h1(256x128) = x(256x256) @ w1(128x256)^T + b1
// ---------------------------------------------------------------------------
__global__ __launch_bounds__(128) void gemm1_k(const float* __restrict__ x,
                                               const float* __restrict__ w1,
                                               const float* __restrict__ b1,
                                               float* __restrict__ h1) {
    __shared__ float xs[256];
    const int m = blockIdx.x, t = threadIdx.x;
    xs[t] = x[m * 256 + t];
    xs[t + 128] = x[m * 256 + 128 + t];
    __syncthreads();
    float acc = b1[t];
    const float4* wr = (const float4*)(w1 + t * 256);
#pragma unroll 8
    for (int k4 = 0; k4 < 64; ++k4) {
        float4 w = wr[k4];
        acc += xs[k4 * 4 + 0] * w.x + xs[k4 * 4 + 1] * w.y +
               xs[k4 * 4 + 2] * w.z + xs[k4 * 4 + 3] * w.w;
    }
    h1[m * 128 + t] = acc;
}

// ---------------------------------------------------------------------------
// GEMM2: h2b = bf16 image of h1 @ w2^T + b2, in BK=32 K-tiles of 16KB.
// byte(m, k) = (k>>5)*16384 + m*64 + ((((k>>3)&3) ^ ((m>>1)&3))<<4) + (k&7)*2
// Granule-XOR ^((m>>1)&3) -> 2-way-only bank aliasing on fragment ds_reads
// (free per m136) while the 16KB tile stays linearly DMA-able.
// ---------------------------------------------------------------------------
__global__ __launch_bounds__(256) void gemm2_k(const float* __restrict__ h1,
                                               const float* __restrict__ w2,
                                               const float* __restrict__ b2,
                                               char* __restrict__ h2b) {
    __shared__ float As[64][129];
    __shared__ float Bs[64][129];
    const int nb = blockIdx.x, mb = blockIdx.y, t = threadIdx.x;
#pragma unroll
    for (int i = 0; i < 8; ++i) {
        int idx = i * 256 + t;
        int row = idx >> 5, c4 = (idx & 31) * 4;
        float4 a = *(const float4*)(h1 + (mb * 64 + row) * 128 + c4);
        As[row][c4 + 0] = a.x; As[row][c4 + 1] = a.y;
        As[row][c4 + 2] = a.z; As[row][c4 + 3] = a.w;
        float4 bv = *(const float4*)(w2 + (nb * 64 + row) * 128 + c4);
        Bs[row][c4 + 0] = bv.x; Bs[row][c4 + 1] = bv.y;
        Bs[row][c4 + 2] = bv.z; Bs[row][c4 + 3] = bv.w;
    }
    __syncthreads();
    const int tx = t & 15, ty = t >> 4;
    float acc[4][4] = {};
#pragma unroll 4
    for (int k = 0; k < 128; ++k) {
        float a[4], b[4];
#pragma unroll
        for (int i = 0; i < 4; ++i) a[i] = As[ty * 4 + i][k];
#pragma unroll
        for (int j = 0; j < 4; ++j) b[j] = Bs[tx * 4 + j][k];
#pragma unroll
        for (int i = 0; i < 4; ++i)
#pragma unroll
            for (int j = 0; j < 4; ++j) acc[i][j] += a[i] * b[j];
    }
#pragma unroll
    for (int i = 0; i < 4; ++i)
#pragma unroll
        for (int j = 0; j < 4; ++j) {
            int m = mb * 64 + ty * 4 + i;
            int n = nb * 64 + tx * 4 + j;   // = gemm3 K index
            float v = acc[i][j] + b2[n];
            int byte = (n >> 5) * 16384 + m * 64 +
                       ((((n >> 3) & 3) ^ ((m >> 1) & 3)) << 4) + (n & 7) * 2;
            *(__bf16*)(h2b + byte) = (__bf16)v;
        }
}

// ---------------------------------------------------------------------------
// GEMM3 v10: 4 blocks/CU. BM=256, BN=32, BK=32, KS=2. grid 1024 (nb 512 x ks 2),
// 256 thr (4 waves, 2Mx2N; wave tile 128x16). LDS 36KB: A dbuf 2x16KB (DMA'd
// linearly from the pre-swizzled image) + W dbuf 2x2KB (fp32->bf16 reg-staged
// by threads 0-127). r6-proven 2-barrier step; occupancy does the hiding.
// Output: bf16 partials (no bias); convsink sums p0+p1+b3.
// ---------------------------------------------------------------------------
__global__ __launch_bounds__(256, 4) void gemm3_k(const char* __restrict__ Ab,
                                                  const float* __restrict__ W,
                                                  char* __restrict__ parts) {
    __shared__ __align__(16) char lds[36864];  // A 2x16384 @0; W 2x2048 @32768
    const int tid = threadIdx.x;
    const int nb = blockIdx.x >> 1, ks = blockIdx.x & 1;
    const int n0 = nb * 32;
    const int k0 = ks * 2048;
    const int lane = tid & 63, wid = tid >> 6;
    const int lr = lane & 15, lq = lane >> 4;
    const int wm = wid >> 1, wn = wid & 1;

#define ISSUE_A(kt, buf)                                                              \
    {                                                                                 \
        const char* _s = Ab + (size_t)(kt) * 16384 + wid * 1024 + lane * 16;          \
        char* _d = lds + (buf) * 16384 + wid * 1024;                                  \
        __builtin_amdgcn_global_load_lds((as1_uint*)(_s), (as3_uint*)(_d), 16, 0, 0);               \
        __builtin_amdgcn_global_load_lds((as1_uint*)(_s + 4096), (as3_uint*)(_d + 4096), 16, 0, 0);   \
        __builtin_amdgcn_global_load_lds((as1_uint*)(_s + 8192), (as3_uint*)(_d + 8192), 16, 0, 0);   \
        __builtin_amdgcn_global_load_lds((as1_uint*)(_s + 12288), (as3_uint*)(_d + 12288), 16, 0, 0); \
    }

    // W staging: threads 0-127 (waves 0,1 - wave-uniform branch).
    // thread -> row n=tid>>2 (0..31), kgroup kg=tid&3 (8 K values).
    const int wn_row = tid >> 2, wkg = tid & 3;
    const float* Wlane = W + (size_t)(n0 + wn_row) * 4096 + k0 + wkg * 8;
    auto loadW = [&](int t, float4& a, float4& b) {
        const float* q = Wlane + t * 32;
        a = *(const float4*)q;
        b = *(const float4*)(q + 4);
    };
    auto storeW = [&](const float4& a, const float4& b, int buf) {
        bf16x8 p;
        p[0] = (__bf16)a.x; p[1] = (__bf16)a.y; p[2] = (__bf16)a.z; p[3] = (__bf16)a.w;
        p[4] = (__bf16)b.x; p[5] = (__bf16)b.y; p[6] = (__bf16)b.z; p[7] = (__bf16)b.w;
        *(bf16x8*)(lds + 32768 + buf * 2048 + wn_row * 64 +
                   ((wkg ^ ((wn_row >> 1) & 3)) << 4)) = p;
    };

    f32x4 acc[8];
    const f32x4 zero = {0.f, 0.f, 0.f, 0.f};
#pragma unroll
    for (int mi = 0; mi < 8; ++mi) acc[mi] = zero;

    const int nW = wn * 16 + lr;
    const int wOff = 32768 + nW * 64 + ((lq ^ ((nW >> 1) & 3)) << 4);

    auto mfma_tile = [&](int buf) {
        const char* Ac = lds + buf * 16384;
        bf16x8 bfv = *(const bf16x8*)(lds + wOff + buf * 2048);
#pragma unroll
        for (int mi = 0; mi < 8; ++mi) {
            int m = wm * 128 + mi * 16 + lr;
            bf16x8 af = *(const bf16x8*)(Ac + m * 64 + ((lq ^ ((m >> 1) & 3)) << 4));
            acc[mi] = __builtin_amdgcn_mfma_f32_16x16x32_bf16(af, bfv, acc[mi], 0, 0, 0);
        }
    };

    // prologue
    {
        float4 a0, b0;
        ISSUE_A(ks * 64, 0);
        if (tid < 128) loadW(0, a0, b0);
        __syncthreads();   // drain: A(0) resident, W regs ready
        if (tid < 128) storeW(a0, b0, 0);
        __syncthreads();   // W(0) visible
    }

#pragma unroll 1
    for (int t = 0; t < 64; ++t) {
        const int cur = t & 1;
        float4 a0, b0;
        if (t < 63) {
            ISSUE_A(ks * 64 + t + 1, cur ^ 1);
            if (tid < 128) loadW(t + 1, a0, b0);
        }
        mfma_tile(cur);
        __syncthreads();   // reads of cur done; drain -> A(t+1) resident
        if (t < 63 && tid < 128) storeW(a0, b0, cur ^ 1);
        __syncthreads();   // buf cur^1 visible
    }
#undef ISSUE_A

    __bf16* P = (__bf16*)(parts + ks * 8388608);
#pragma unroll
    for (int mi = 0; mi < 8; ++mi) {
        const int n = n0 + wn * 16 + lr;
#pragma unroll
        for (int r = 0; r < 4; ++r) {
            int m = wm * 128 + mi * 16 + lq * 4 + r;
            P[m * 16384 + n] = (__bf16)acc[mi][r];
        }
    }
}

// ---------------------------------------------------------------------------
// Fused conv x5 (bf16 MFMA) + square + Sinkhorn. One block per batch element.
// Staging sums the two gemm3 partials and adds b3.
// ---------------------------------------------------------------------------
template <int CIN, int COUT, int DIL, int MT, int NT>
__device__ __forceinline__ void conv_core(const char* xt, char* wl,
                                          const float* __restrict__ w,
                                          f32x4 (&acc)[MT][NT], int tid) {
    constexpr int RB = CIN * 2;
    const int lane = tid & 63, wid = tid >> 6;
    const int lr = lane & 15, lq = lane >> 4;
    const int cobase = wid * (COUT / 4);
    const f32x4 zero = {0.f, 0.f, 0.f, 0.f};
#pragma unroll
    for (int mi = 0; mi < MT; ++mi)
#pragma unroll
        for (int ni = 0; ni < NT; ++ni) acc[mi][ni] = zero;

    for (int cic = 0; cic < CIN / 32; ++cic) {
        for (int idx = tid; idx < COUT * 4; idx += 256) {
            int co = idx >> 2, cib = idx & 3, ci0 = cic * 32 + cib * 8;
            const float* src = w + co * (CIN * 3) + ci0 * 3;
            float v[24];
#pragma unroll
            for (int u = 0; u < 6; ++u) {
                float4 f = *(const float4*)(src + u * 4);
                v[u * 4 + 0] = f.x; v[u * 4 + 1] = f.y;
                v[u * 4 + 2] = f.z; v[u * 4 + 3] = f.w;
            }
#pragma unroll
            for (int tp = 0; tp < 3; ++tp) {
                bf16x8 pk;
#pragma unroll
                for (int j = 0; j < 8; ++j) pk[j] = (__bf16)v[j * 3 + tp];
                *(bf16x8*)(wl + ((tp * 4 + cib) * COUT + co) * 16) = pk;
            }
        }
        __syncthreads();
#pragma unroll
        for (int tp = 0; tp < 3; ++tp) {
            bf16x8 af[MT];
#pragma unroll
            for (int mi = 0; mi < MT; ++mi)
                af[mi] = *(const bf16x8*)(wl + ((tp * 4 + lq) * COUT + cobase + mi * 16 + lr) * 16);
            bf16x8 bfr[NT];
#pragma unroll
            for (int ni = 0; ni < NT; ++ni) {
                int colX = ni * 16 + lr + tp * DIL;
                bfr[ni] = *(const bf16x8*)(xt + ((colX * RB + (cic * 4 + lq) * 16) ^ ((colX & 7) << 4)));
            }
#pragma unroll
            for (int mi = 0; mi < MT; ++mi)
#pragma unroll
                for (int ni = 0; ni < NT; ++ni)
                    acc[mi][ni] = __builtin_amdgcn_mfma_f32_16x16x32_bf16(
                        af[mi], bfr[ni], acc[mi][ni], 0, 0, 0);
        }
        __syncthreads();
    }
}

template <int COUT, int LOUT, int MT, int NT>
__device__ __forceinline__ void write_xt(char* xt_out, const f32x4 (&acc)[MT][NT],
                                         const float* __restrict__ bias, int tid) {
    constexpr int RBO = COUT * 2;
    const int lane = tid & 63, wid = tid >> 6;
    const int lr = lane & 15, lq = lane >> 4;
    const int cobase = wid * (COUT / 4);
#pragma unroll
    for (int mi = 0; mi < MT; ++mi)
#pragma unroll
        for (int ni = 0; ni < NT; ++ni) {
            int l = ni * 16 + lr;
            if (l < LOUT) {
#pragma unroll
                for (int r = 0; r < 4; ++r) {
                    int co = cobase + mi * 16 + lq * 4 + r;
                    float y = acc[mi][ni][r] + bias[co];
                    int byte = (l * RBO + ((co >> 3) << 4) + (co & 7) * 2) ^ ((l & 7) << 4);
                    *(__bf16*)(xt_out + byte) = (__bf16)y;
                }
            }
        }
}

__global__ __launch_bounds__(256, 1) void convsink_k(
    const char* __restrict__ parts, const float* __restrict__ b3,
    const float* __restrict__ cw1, const float* __restrict__ cb1,
    const float* __restrict__ cw2, const float* __restrict__ cb2,
    const float* __restrict__ cw3, const float* __restrict__ cb3,
    const float* __restrict__ cw4, const float* __restrict__ cb4,
    const float* __restrict__ cw5, const float* __restrict__ cb5,
    float* __restrict__ out) {
    __shared__ __align__(16) char lds[34816 + 31488 + 36864 + 16640];
    char* xtA = lds;
    char* xtB = lds + 34816;
    char* wl = lds + 34816 + 31488;
    float* S = (float*)(lds + 34816 + 31488 + 36864);

    const int b = blockIdx.x, tid = threadIdx.x;
    const __bf16* p0 = (const __bf16*)parts + (size_t)b * 16384;
    const __bf16* p1 = (const __bf16*)(parts + 8388608) + (size_t)b * 16384;

#pragma unroll
    for (int i = 0; i < 8; ++i) {
        int idx = i * 256 + tid;
        int l = idx & 127, cib = idx >> 7;
        bf16x8 p;
#pragma unroll
        for (int j = 0; j < 8; ++j) {
            int n = (cib * 8 + j) * 128 + l;
            float v = (float)p0[n] + (float)p1[n] + b3[n];
            p[j] = (__bf16)v;
        }
        *(bf16x8*)(xtA + ((l * 256 + cib * 16) ^ ((l & 7) << 4))) = p;
    }
    __syncthreads();

    {
        f32x4 acc[3][5];
        conv_core<128, 192, 28, 3, 5>(xtA, wl, cw1, acc, tid);
        write_xt<192, 72, 3, 5>(xtB, acc, cb1, tid);
    }
    __syncthreads();
    {
        f32x4 acc[2][5];
        conv_core<192, 128, 1, 2, 5>(xtB, wl, cw2, acc, tid);
        write_xt<128, 70, 2, 5>(xtA, acc, cb2, tid);
    }
    __syncthreads();
    {
        f32x4 acc[1][5];
        conv_core<128, 64, 1, 1, 5>(xtA, wl, cw3, acc, tid);
        write_xt<64, 68, 1, 5>(xtB, acc, cb3, tid);
    }
    __syncthreads();
    {
        f32x4 acc[1][5];
        conv_core<64, 64, 1, 1, 5>(xtB, wl, cw4, acc, tid);
        write_xt<64, 66, 1, 5>(xtA, acc, cb4, tid);
    }
    __syncthreads();
    {
        f32x4 acc[1][4];
        conv_core<64, 64, 1, 1, 4>(xtA, wl, cw5, acc, tid);
        const int lane = tid & 63, wid = tid >> 6;
        const int lr = lane & 15, lq = lane >> 4;
        const int cobase = wid * 16;
#pragma unroll
        for (int ni = 0; ni < 4; ++ni) {
            int l = ni * 16 + lr;
#pragma unroll
            for (int r = 0; r < 4; ++r) {
                int co = cobase + lq * 4 + r;
                float y = acc[0][ni][r] + cb5[co];
                S[co * 65 + l] = y * y + 0.001f;
            }
        }
    }
    __syncthreads();

    const int q = tid & 3, rid = tid >> 2;
    for (int it = 0; it < 10; ++it) {
        float p = 0.f;
#pragma unroll
        for (int j = 0; j < 16; ++j) p += S[rid * 65 + q * 16 + j];
        p += __shfl_xor(p, 1);
        p += __shfl_xor(p, 2);
        float inv = 1.0f / p;
#pragma unroll
        for (int j = 0; j < 16; ++j) S[rid * 65 + q * 16 + j] *= inv;
        __syncthreads();
        float c = 0.f;
#pragma unroll
        for (int i = 0; i < 16; ++i) c += S[(q * 16 + i) * 65 + rid];
        c += __shfl_xor(c, 1);
        c += __shfl_xor(c, 2);
        float invc = 1.0f / c;
#pragma unroll
        for (int i = 0; i < 16; ++i) S[(q * 16 + i) * 65 + rid] *= invc;
        __syncthreads();
    }

#pragma unroll
    for (int i = 0; i < 16; ++i) {
        int idx = i * 256 + tid;
        out[b * 4096 + idx] = S[(idx >> 6) * 65 + (idx & 63)];
    }
}

// ---------------------------------------------------------------------------
extern "C" void kernel_launch(void* const* d_in, const int* in_sizes, int n_in,
                              void* d_out, int out_size, void* d_ws, size_t ws_size,
                              hipStream_t stream) {
    const float* x = (const float*)d_in[0];
    const float* w1 = (const float*)d_in[1];
    const float* b1 = (const float*)d_in[2];
    const float* w2 = (const float*)d_in[3];
    const float* b2 = (const float*)d_in[4];
    const float* w3 = (const float*)d_in[5];
    const float* b3 = (const float*)d_in[6];
    const float* cw1 = (const float*)d_in[7];
    const float* cb1 = (const float*)d_in[8];
    const float* cw2 = (const float*)d_in[9];
    const float* cb2 = (const float*)d_in[10];
    const float* cw3 = (const float*)d_in[11];
    const float* cb3 = (const float*)d_in[12];
    const float* cw4 = (const float*)d_in[13];
    const float* cb4 = (const float*)d_in[14];
    const float* cw5 = (const float*)d_in[15];
    const float* cb5 = (const float*)d_in[16];
    float* out = (float*)d_out;

    char* ws = (char*)d_ws;
    float* h1 = (float*)(ws);             // 131072 B
    char* h2b = ws + 131072;              // 2 MB bf16 image (BK=32 tiles)
    char* parts = ws + 131072 + 2097152;  // 2 x 8 MB bf16 partials

    gemm1_k<<<256, 128, 0, stream>>>(x, w1, b1, h1);
    gemm2_k<<<dim3(64, 4), 256, 0, stream>>>(h1, w2, b2, h2b);
    gemm3_k<<<1024, 256, 0, stream>>>(h2b, w3, parts);
    convsink_k<<<256, 256, 0, stream>>>(parts, b3, cw1, cb1, cw2, cb2,
                                        cw3, cb3, cw4, cb4, cw5, cb5, out);
}

// Round 12
// 142.406 us; speedup vs baseline: 1.4695x; 1.0808x over previous
//
#include <hip/hip_runtime.h>
#include <hip/hip_bf16.h>

typedef float f32x4 __attribute__((ext_vector_type(4)));
typedef __bf16 bf16x8 __attribute__((ext_vector_type(8)));

typedef __attribute__((address_space(1))) const unsigned int as1_uint;
typedef __attribute__((address_space(3))) unsigned int as3_uint;

// ---------------------------------------------------------------------------
// GEMM1: h1(256x128) = x(256x256) @ w1(128x256)^T + b1
// ---------------------------------------------------------------------------
__global__ __launch_bounds__(128) void gemm1_k(const float* __restrict__ x,
                                               const float* __restrict__ w1,
                                               const float* __restrict__ b1,
                                               float* __restrict__ h1) {
    __shared__ float xs[256];
    const int m = blockIdx.x, t = threadIdx.x;
    xs[t] = x[m * 256 + t];
    xs[t + 128] = x[m * 256 + 128 + t];
    __syncthreads();
    float acc = b1[t];
    const float4* wr = (const float4*)(w1 + t * 256);
#pragma unroll 8
    for (int k4 = 0; k4 < 64; ++k4) {
        float4 w = wr[k4];
        acc += xs[k4 * 4 + 0] * w.x + xs[k4 * 4 + 1] * w.y +
               xs[k4 * 4 + 2] * w.z + xs[k4 * 4 + 3] * w.w;
    }
    h1[m * 128 + t] = acc;
}

// ---------------------------------------------------------------------------
// GEMM2: h2b = bf16 image of h1 @ w2^T + b2, in BK=32 K-tiles of 16KB.
// byte(m, k) = (k>>5)*16384 + m*64 + ((((k>>3)&3) ^ ((m>>1)&3))<<4) + (k&7)*2
// (2-way-only bank aliasing on fragment reads; tile linearly DMA-able)
// ---------------------------------------------------------------------------
__global__ __launch_bounds__(256) void gemm2_k(const float* __restrict__ h1,
                                               const float* __restrict__ w2,
                                               const float* __restrict__ b2,
                                               char* __restrict__ h2b) {
    __shared__ float As[64][129];
    __shared__ float Bs[64][129];
    const int nb = blockIdx.x, mb = blockIdx.y, t = threadIdx.x;
#pragma unroll
    for (int i = 0; i < 8; ++i) {
        int idx = i * 256 + t;
        int row = idx >> 5, c4 = (idx & 31) * 4;
        float4 a = *(const float4*)(h1 + (mb * 64 + row) * 128 + c4);
        As[row][c4 + 0] = a.x; As[row][c4 + 1] = a.y;
        As[row][c4 + 2] = a.z; As[row][c4 + 3] = a.w;
        float4 bv = *(const float4*)(w2 + (nb * 64 + row) * 128 + c4);
        Bs[row][c4 + 0] = bv.x; Bs[row][c4 + 1] = bv.y;
        Bs[row][c4 + 2] = bv.z; Bs[row][c4 + 3] = bv.w;
    }
    __syncthreads();
    const int tx = t & 15, ty = t >> 4;
    float acc[4][4] = {};
#pragma unroll 4
    for (int k = 0; k < 128; ++k) {
        float a[4], b[4];
#pragma unroll
        for (int i = 0; i < 4; ++i) a[i] = As[ty * 4 + i][k];
#pragma unroll
        for (int j = 0; j < 4; ++j) b[j] = Bs[tx * 4 + j][k];
#pragma unroll
        for (int i = 0; i < 4; ++i)
#pragma unroll
            for (int j = 0; j < 4; ++j) acc[i][j] += a[i] * b[j];
    }
#pragma unroll
    for (int i = 0; i < 4; ++i)
#pragma unroll
        for (int j = 0; j < 4; ++j) {
            int m = mb * 64 + ty * 4 + i;
            int n = nb * 64 + tx * 4 + j;   // = gemm3 K index
            float v = acc[i][j] + b2[n];
            int byte = (n >> 5) * 16384 + m * 64 +
                       ((((n >> 3) & 3) ^ ((m >> 1) & 3)) << 4) + (n & 7) * 2;
            *(__bf16*)(h2b + byte) = (__bf16)v;
        }
}

// ---------------------------------------------------------------------------
// GEMM3 v11: ring-3 DMA on BOTH operands, counted vmcnt(3), ONE barrier/step,
// 2 blocks/CU. BM=256, BN=64, BK=32, KS=2 -> grid 512, 512 thr (8 waves 4Mx2N,
// wave tile 64x32). LDS 72KB: A ring 3x16KB (linear DMA from pre-swizzled
// image) + W ring 3x8KB fp32 (DMA w/ source-seg XOR; cvt at fragment read).
// Per step t: issue 3 DMAs for tile t+2 ; MFMA(t) ; vmcnt(3) retires t+1,
// t+2 STAYS IN FLIGHT across the barrier ; s_barrier. Zero staging VALU.
// Output: bf16 partials; convsink sums p0+p1+b3.
// ---------------------------------------------------------------------------
__global__ __launch_bounds__(512, 4) void gemm3_k(const char* __restrict__ Ab,
                                                  const float* __restrict__ W,
                                                  char* __restrict__ parts) {
    __shared__ __align__(16) char lds[73728];  // A 3x16384 @0; W 3x8192 @49152
    const int tid = threadIdx.x;
    const int nb = blockIdx.x >> 1, ks = blockIdx.x & 1;
    const int n0 = nb * 64;
    const int kt0 = ks * 64;   // global K-tile (32-wide) base; 64 tiles per block
    const int lane = tid & 63, wid = tid >> 6;
    const int lr = lane & 15, lq = lane >> 4;
    const int wm = wid >> 1, wn = wid & 1;

    // W DMA source: thread stages row wr, dest-seg wseg; source seg = wseg ^ (wr&7)
    const int wr_ = wid * 8 + (lane >> 3);
    const int wseg = lane & 7;
    const char* Wsrc = (const char*)W + (size_t)(n0 + wr_) * 16384 +
                       ((wseg ^ (wr_ & 7)) << 4);

#define ISSUE(kt, s)                                                                   \
    {                                                                                  \
        const char* _a = Ab + (size_t)(kt) * 16384 + wid * 2048 + lane * 16;           \
        char* _ad = lds + (s) * 16384 + wid * 2048;                                    \
        __builtin_amdgcn_global_load_lds((as1_uint*)(_a), (as3_uint*)(_ad), 16, 0, 0);               \
        __builtin_amdgcn_global_load_lds((as1_uint*)(_a + 1024), (as3_uint*)(_ad + 1024), 16, 0, 0); \
        const char* _w = Wsrc + (size_t)(kt) * 128;                                    \
        char* _wd = lds + 49152 + (s) * 8192 + wid * 1024;                             \
        __builtin_amdgcn_global_load_lds((as1_uint*)(_w), (as3_uint*)(_wd), 16, 0, 0);               \
    }

    f32x4 acc[4][2];
    const f32x4 zero = {0.f, 0.f, 0.f, 0.f};
#pragma unroll
    for (int mi = 0; mi < 4; ++mi)
#pragma unroll
        for (int ni = 0; ni < 2; ++ni) acc[mi][ni] = zero;

    auto mfma_tile = [&](int s) {
        const char* Ac = lds + s * 16384;
        const char* Wc = lds + 49152 + s * 8192;
        bf16x8 bfv[2];
#pragma unroll
        for (int ni = 0; ni < 2; ++ni) {
            int n = wn * 32 + ni * 16 + lr;
            int sw = n & 7;
            float4 f0 = *(const float4*)(Wc + n * 128 + (((2 * lq) ^ sw) << 4));
            float4 f1 = *(const float4*)(Wc + n * 128 + (((2 * lq + 1) ^ sw) << 4));
            bf16x8 p;
            p[0] = (__bf16)f0.x; p[1] = (__bf16)f0.y; p[2] = (__bf16)f0.z; p[3] = (__bf16)f0.w;
            p[4] = (__bf16)f1.x; p[5] = (__bf16)f1.y; p[6] = (__bf16)f1.z; p[7] = (__bf16)f1.w;
            bfv[ni] = p;
        }
#pragma unroll
        for (int mi = 0; mi < 4; ++mi) {
            int m = wm * 64 + mi * 16 + lr;
            bf16x8 af = *(const bf16x8*)(Ac + m * 64 + ((lq ^ ((m >> 1) & 3)) << 4));
            acc[mi][0] = __builtin_amdgcn_mfma_f32_16x16x32_bf16(af, bfv[0], acc[mi][0], 0, 0, 0);
            acc[mi][1] = __builtin_amdgcn_mfma_f32_16x16x32_bf16(af, bfv[1], acc[mi][1], 0, 0, 0);
        }
    };

    // prologue: tiles kt0, kt0+1 in flight; retire tile kt0 (keep kt0+1)
    ISSUE(kt0, 0);
    ISSUE(kt0 + 1, 1);
    asm volatile("s_waitcnt vmcnt(3)" ::: "memory");
    __builtin_amdgcn_sched_barrier(0);
    __builtin_amdgcn_s_barrier();

    int s = 0, s2 = 2;
#pragma unroll 1
    for (int t = 0; t < 64; ++t) {
        if (t < 62) ISSUE(kt0 + t + 2, s2);
        mfma_tile(s);
        if (t < 62) {
            asm volatile("s_waitcnt vmcnt(3)" ::: "memory");   // retire t+1; t+2 flies
        } else if (t == 62) {
            asm volatile("s_waitcnt vmcnt(0)" ::: "memory");   // drain t+1 (=63)
        }
        __builtin_amdgcn_sched_barrier(0);
        if (t < 63) __builtin_amdgcn_s_barrier();
        s = (s == 2) ? 0 : s + 1;
        s2 = (s2 == 2) ? 0 : s2 + 1;
    }
#undef ISSUE

    __bf16* P = (__bf16*)(parts + ks * 8388608);
#pragma unroll
    for (int mi = 0; mi < 4; ++mi)
#pragma unroll
        for (int ni = 0; ni < 2; ++ni) {
            const int n = n0 + wn * 32 + ni * 16 + lr;
#pragma unroll
            for (int r = 0; r < 4; ++r) {
                int m = wm * 64 + mi * 16 + lq * 4 + r;
                P[m * 16384 + n] = (__bf16)acc[mi][ni][r];
            }
        }
}

// ---------------------------------------------------------------------------
// Fused conv x5 (bf16 MFMA) + square + Sinkhorn. One block per batch element.
// Staging sums the two gemm3 partials and adds b3.
// ---------------------------------------------------------------------------
template <int CIN, int COUT, int DIL, int MT, int NT>
__device__ __forceinline__ void conv_core(const char* xt, char* wl,
                                          const float* __restrict__ w,
                                          f32x4 (&acc)[MT][NT], int tid) {
    constexpr int RB = CIN * 2;
    const int lane = tid & 63, wid = tid >> 6;
    const int lr = lane & 15, lq = lane >> 4;
    const int cobase = wid * (COUT / 4);
    const f32x4 zero = {0.f, 0.f, 0.f, 0.f};
#pragma unroll
    for (int mi = 0; mi < MT; ++mi)
#pragma unroll
        for (int ni = 0; ni < NT; ++ni) acc[mi][ni] = zero;

    for (int cic = 0; cic < CIN / 32; ++cic) {
        for (int idx = tid; idx < COUT * 4; idx += 256) {
            int co = idx >> 2, cib = idx & 3, ci0 = cic * 32 + cib * 8;
            const float* src = w + co * (CIN * 3) + ci0 * 3;
            float v[24];
#pragma unroll
            for (int u = 0; u < 6; ++u) {
                float4 f = *(const float4*)(src + u * 4);
                v[u * 4 + 0] = f.x; v[u * 4 + 1] = f.y;
                v[u * 4 + 2] = f.z; v[u * 4 + 3] = f.w;
            }
#pragma unroll
            for (int tp = 0; tp < 3; ++tp) {
                bf16x8 pk;
#pragma unroll
                for (int j = 0; j < 8; ++j) pk[j] = (__bf16)v[j * 3 + tp];
                *(bf16x8*)(wl + ((tp * 4 + cib) * COUT + co) * 16) = pk;
            }
        }
        __syncthreads();
#pragma unroll
        for (int tp = 0; tp < 3; ++tp) {
            bf16x8 af[MT];
#pragma unroll
            for (int mi = 0; mi < MT; ++mi)
                af[mi] = *(const bf16x8*)(wl + ((tp * 4 + lq) * COUT + cobase + mi * 16 + lr) * 16);
            bf16x8 bfr[NT];
#pragma unroll
            for (int ni = 0; ni < NT; ++ni) {
                int colX = ni * 16 + lr + tp * DIL;
                bfr[ni] = *(const bf16x8*)(xt + ((colX * RB + (cic * 4 + lq) * 16) ^ ((colX & 7) << 4)));
            }
#pragma unroll
            for (int mi = 0; mi < MT; ++mi)
#pragma unroll
                for (int ni = 0; ni < NT; ++ni)
                    acc[mi][ni] = __builtin_amdgcn_mfma_f32_16x16x32_bf16(
                        af[mi], bfr[ni], acc[mi][ni], 0, 0, 0);
        }
        __syncthreads();
    }
}

template <int COUT, int LOUT, int MT, int NT>
__device__ __forceinline__ void write_xt(char* xt_out, const f32x4 (&acc)[MT][NT],
                                         const float* __restrict__ bias, int tid) {
    constexpr int RBO = COUT * 2;
    const int lane = tid & 63, wid = tid >> 6;
    const int lr = lane & 15, lq = lane >> 4;
    const int cobase = wid * (COUT / 4);
#pragma unroll
    for (int mi = 0; mi < MT; ++mi)
#pragma unroll
        for (int ni = 0; ni < NT; ++ni) {
            int l = ni * 16 + lr;
            if (l < LOUT) {
#pragma unroll
                for (int r = 0; r < 4; ++r) {
                    int co = cobase + mi * 16 + lq * 4 + r;
                    float y = acc[mi][ni][r] + bias[co];
                    int byte = (l * RBO + ((co >> 3) << 4) + (co & 7) * 2) ^ ((l & 7) << 4);
                    *(__bf16*)(xt_out + byte) = (__bf16)y;
                }
            }
        }
}

__global__ __launch_bounds__(256, 1) void convsink_k(
    const char* __restrict__ parts, const float* __restrict__ b3,
    const float* __restrict__ cw1, const float* __restrict__ cb1,
    const float* __restrict__ cw2, const float* __restrict__ cb2,
    const float* __restrict__ cw3, const float* __restrict__ cb3,
    const float* __restrict__ cw4, const float* __restrict__ cb4,
    const float* __restrict__ cw5, const float* __restrict__ cb5,
    float* __restrict__ out) {
    __shared__ __align__(16) char lds[34816 + 31488 + 36864 + 16640];
    char* xtA = lds;
    char* xtB = lds + 34816;
    char* wl = lds + 34816 + 31488;
    float* S = (float*)(lds + 34816 + 31488 + 36864);

    const int b = blockIdx.x, tid = threadIdx.x;
    const __bf16* p0 = (const __bf16*)parts + (size_t)b * 16384;
    const __bf16* p1 = (const __bf16*)(parts + 8388608) + (size_t)b * 16384;

#pragma unroll
    for (int i = 0; i < 8; ++i) {
        int idx = i * 256 + tid;
        int l = idx & 127, cib = idx >> 7;
        bf16x8 p;
#pragma unroll
        for (int j = 0; j < 8; ++j) {
            int n = (cib * 8 + j) * 128 + l;
            float v = (float)p0[n] + (float)p1[n] + b3[n];
            p[j] = (__bf16)v;
        }
        *(bf16x8*)(xtA + ((l * 256 + cib * 16) ^ ((l & 7) << 4))) = p;
    }
    __syncthreads();

    {
        f32x4 acc[3][5];
        conv_core<128, 192, 28, 3, 5>(xtA, wl, cw1, acc, tid);
        write_xt<192, 72, 3, 5>(xtB, acc, cb1, tid);
    }
    __syncthreads();
    {
        f32x4 acc[2][5];
        conv_core<192, 128, 1, 2, 5>(xtB, wl, cw2, acc, tid);
        write_xt<128, 70, 2, 5>(xtA, acc, cb2, tid);
    }
    __syncthreads();
    {
        f32x4 acc[1][5];
        conv_core<128, 64, 1, 1, 5>(xtA, wl, cw3, acc, tid);
        write_xt<64, 68, 1, 5>(xtB, acc, cb3, tid);
    }
    __syncthreads();
    {
        f32x4 acc[1][5];
        conv_core<64, 64, 1, 1, 5>(xtB, wl, cw4, acc, tid);
        write_xt<64, 66, 1, 5>(xtA, acc, cb4, tid);
    }
    __syncthreads();
    {
        f32x4 acc[1][4];
        conv_core<64, 64, 1, 1, 4>(xtA, wl, cw5, acc, tid);
        const int lane = tid & 63, wid = tid >> 6;
        const int lr = lane & 15, lq = lane >> 4;
        const int cobase = wid * 16;
#pragma unroll
        for (int ni = 0; ni < 4; ++ni) {
            int l = ni * 16 + lr;
#pragma unroll
            for (int r = 0; r < 4; ++r) {
                int co = cobase + lq * 4 + r;
                float y = acc[0][ni][r] + cb5[co];
                S[co * 65 + l] = y * y + 0.001f;
            }
        }
    }
    __syncthreads();

    const int q = tid & 3, rid = tid >> 2;
    for (int it = 0; it < 10; ++it) {
        float p = 0.f;
#pragma unroll
        for (int j = 0; j < 16; ++j) p += S[rid * 65 + q * 16 + j];
        p += __shfl_xor(p, 1);
        p += __shfl_xor(p, 2);
        float inv = 1.0f / p;
#pragma unroll
        for (int j = 0; j < 16; ++j) S[rid * 65 + q * 16 + j] *= inv;
        __syncthreads();
        float c = 0.f;
#pragma unroll
        for (int i = 0; i < 16; ++i) c += S[(q * 16 + i) * 65 + rid];
        c += __shfl_xor(c, 1);
        c += __shfl_xor(c, 2);
        float invc = 1.0f / c;
#pragma unroll
        for (int i = 0; i < 16; ++i) S[(q * 16 + i) * 65 + rid] *= invc;
        __syncthreads();
    }

#pragma unroll
    for (int i = 0; i < 16; ++i) {
        int idx = i * 256 + tid;
        out[b * 4096 + idx] = S[(idx >> 6) * 65 + (idx & 63)];
    }
}

// ---------------------------------------------------------------------------
extern "C" void kernel_launch(void* const* d_in, const int* in_sizes, int n_in,
                              void* d_out, int out_size, void* d_ws, size_t ws_size,
                              hipStream_t stream) {
    const float* x = (const float*)d_in[0];
    const float* w1 = (const float*)d_in[1];
    const float* b1 = (const float*)d_in[2];
    const float* w2 = (const float*)d_in[3];
    const float* b2 = (const float*)d_in[4];
    const float* w3 = (const float*)d_in[5];
    const float* b3 = (const float*)d_in[6];
    const float* cw1 = (const float*)d_in[7];
    const float* cb1 = (const float*)d_in[8];
    const float* cw2 = (const float*)d_in[9];
    const float* cb2 = (const float*)d_in[10];
    const float* cw3 = (const float*)d_in[11];
    const float* cb3 = (const float*)d_in[12];
    const float* cw4 = (const float*)d_in[13];
    const float* cb4 = (const float*)d_in[14];
    const float* cw5 = (const float*)d_in[15];
    const float* cb5 = (const float*)d_in[16];
    float* out = (float*)d_out;

    char* ws = (char*)d_ws;
    float* h1 = (float*)(ws);             // 131072 B
    char* h2b = ws + 131072;              // 2 MB bf16 image (BK=32 tiles)
    char* parts = ws + 131072 + 2097152;  // 2 x 8 MB bf16 partials

    gemm1_k<<<256, 128, 0, stream>>>(x, w1, b1, h1);
    gemm2_k<<<dim3(64, 4), 256, 0, stream>>>(h1, w2, b2, h2b);
    gemm3_k<<<512, 512, 0, stream>>>(h2b, w3, parts);
    convsink_k<<<256, 256, 0, stream>>>(parts, b3, cw1, cb1, cw2, cb2,
                                        cw3, cb3, cw4, cb4, cw5, cb5, out);
}